// Round 4
// baseline (236.631 us; speedup 1.0000x reference)
//
#include <hip/hip_runtime.h>
#include <hip/hip_fp16.h>
#include <math.h>

typedef _Float16 f16x8 __attribute__((ext_vector_type(8)));
typedef float    f32x4 __attribute__((ext_vector_type(4)));
typedef unsigned int u32x4 __attribute__((ext_vector_type(4)));
typedef unsigned short u16;
typedef unsigned int   u32;

#define MFMA_F16(a, b, c) __builtin_amdgcn_mfma_f32_16x16x32_f16((a), (b), (c), 0, 0, 0)

#define NSP 4096
// (1/sqrt(32)) * log2(e): fold softmax scale and exp2 conversion into Q
#define QK_SCALE (0.17677669529663687f * 1.4426950408889634f)

__device__ __forceinline__ float fexp2(float x) {
#if __has_builtin(__builtin_amdgcn_exp2f)
  return __builtin_amdgcn_exp2f(x);
#else
  return exp2f(x);
#endif
}

__device__ __forceinline__ u32 pk_f16(float a, float b) {
#if __has_builtin(__builtin_amdgcn_cvt_pkrtz)
  return __builtin_bit_cast(u32, __builtin_amdgcn_cvt_pkrtz(a, b));
#else
  u16 lo = __builtin_bit_cast(u16, (_Float16)a);
  u16 hi = __builtin_bit_cast(u16, (_Float16)b);
  return (u32)lo | ((u32)hi << 16);
#endif
}

__device__ __forceinline__ u16 f16bits(float a) {
  return __builtin_bit_cast(u16, (_Float16)a);
}

// ---------------------------------------------------------------------------
// Kernel A: QKV projection.  out[384][4096] = [Wq;Wk;Wv][384][256] @ x[256][4096]
// per batch, fp16 MFMA, fp32 accum.  Q,K stored [bh][n][32] (fp16 bits),
// V stored transposed [bh][32][n] with a per-32-column MFMA permutation
// (kv j -> slot s = ((j>>2)&3)*8 + ((j>>4)&1)*4 + (j&3)) so the attention
// kernel's PV B-fragment is lane-local (no LDS / shuffles for P).
// ---------------------------------------------------------------------------
__global__ __launch_bounds__(512) void qkv_proj_kernel(
    const float* __restrict__ x, const float* __restrict__ Wq,
    const float* __restrict__ Wk, const float* __restrict__ Wv,
    u16* __restrict__ Qo, u16* __restrict__ Ko, u16* __restrict__ Vo)
{
  const int b  = blockIdx.y;
  const int j0 = blockIdx.x * 64;
  const int tid  = threadIdx.x;
  const int wave = tid >> 6, lane = tid & 63;
  const int g = lane >> 4, r = lane & 15;
  const float* xb = x + (size_t)b * 256 * NSP;

  const f32x4 ZERO4 = {0.f, 0.f, 0.f, 0.f};
  f32x4 acc[3][4];
#pragma unroll
  for (int m = 0; m < 3; ++m)
#pragma unroll
    for (int n = 0; n < 4; ++n) acc[m][n] = ZERO4;

  for (int kc = 0; kc < 8; ++kc) {
    f16x8 bfrag[4];
#pragma unroll
    for (int nt = 0; nt < 4; ++nt) {
      const float* src = xb + (size_t)(kc * 32 + g * 8) * NSP + j0 + nt * 16 + r;
      f16x8 f;
#pragma unroll
      for (int i = 0; i < 8; ++i) f[i] = (_Float16)src[(size_t)i * NSP];
      bfrag[nt] = f;
    }
#pragma unroll
    for (int mm = 0; mm < 3; ++mm) {
      const int o_tile = wave * 48 + mm * 16;
      const float* wsrc = (o_tile < 128) ? Wq : ((o_tile < 256) ? Wk : Wv);
      const float* arow = wsrc + ((o_tile & 127) + r) * 256 + kc * 32 + g * 8;
      f16x8 af;
#pragma unroll
      for (int i = 0; i < 8; ++i) af[i] = (_Float16)arow[i];
#pragma unroll
      for (int nt = 0; nt < 4; ++nt)
        acc[mm][nt] = MFMA_F16(af, bfrag[nt], acc[mm][nt]);
    }
  }

  // D layout: row(o) = g*4+i, col(j) = r
#pragma unroll
  for (int mm = 0; mm < 3; ++mm) {
    const int o_tile = wave * 48 + mm * 16;
    const int part = o_tile >> 7;            // 0=Q 1=K 2=V
    const int o_in = o_tile & 127;
    const int head = o_in >> 5;
    const int dbase = (o_in & 31) + g * 4;
#pragma unroll
    for (int nt = 0; nt < 4; ++nt) {
      const int j = j0 + nt * 16 + r;
      if (part < 2) {
        u16* dst = (part == 0) ? Qo : Ko;
        const float sc = (part == 0) ? QK_SCALE : 1.0f;
        const size_t base = ((size_t)((b * 4 + head) * NSP + j)) * 32 + dbase;
        const u32 p01 = pk_f16(acc[mm][nt][0] * sc, acc[mm][nt][1] * sc);
        const u32 p23 = pk_f16(acc[mm][nt][2] * sc, acc[mm][nt][3] * sc);
        *(u32*)(dst + base)     = p01;
        *(u32*)(dst + base + 2) = p23;
      } else {
        // permuted V store: within each 32-col block, kv j -> slot s
        const int jb = j & ~31, off = j & 31;
        const int s = (((off >> 2) & 3) << 3) | (((off >> 4) & 1) << 2) | (off & 3);
#pragma unroll
        for (int i = 0; i < 4; ++i)
          Vo[((size_t)((b * 4 + head) * 32 + dbase + i)) * NSP + jb + s] =
              f16bits(acc[mm][nt][i]);
      }
    }
  }
}

// ---------------------------------------------------------------------------
// Kernel B: flash attention, swapped-operand MFMA, fully register-resident P.
// grid 1024 blocks x 256 threads (4 waves, 16 q-rows each), KV block = 64.
// S^T = mfma(K, Q): lane (g,r) holds q-row r, kv = kv0 + n*16 + g*4 + i.
// PV:  Oc = mfma(Vperm, Ppacked): k-enumeration permuted identically on both
//      operands (V pre-permuted in memory) so P never leaves the lane.
// l  = mfma(ones, Ppacked): row-sum of P on the matrix pipe.
// No LDS. No __syncthreads. T13 defer-max (threshold 8).
// ---------------------------------------------------------------------------
__global__ __launch_bounds__(256) void attn_kernel(
    const u16* __restrict__ Qg, const u16* __restrict__ Kg,
    const u16* __restrict__ Vg, float* __restrict__ att)
{
  // XCD swizzle: 1024 blocks; XCD = d&7 gets two full bh (K/V ~1MB in 4MB L2)
  const int d  = blockIdx.x;
  const int bh = (d & 7) * 2 + ((d >> 3) & 1);
  const int qt = d >> 4;                  // 0..63
  const int wave = threadIdx.x >> 6, lane = threadIdx.x & 63;
  const int g = lane >> 4, r = lane & 15;
  const int q0 = qt * 64 + wave * 16;     // this wave's 16 q-rows

  const size_t qkbase = (size_t)bh * NSP * 32;
  const u16* Kp = Kg + qkbase;                  // [n][32]
  const u16* Vp = Vg + (size_t)bh * 32 * NSP;   // [32][n] permuted per 32-block

  const f16x8 qf = *(const f16x8*)(Qg + qkbase + (size_t)(q0 + r) * 32 + g * 8);

  const f32x4 ZERO4 = {0.f, 0.f, 0.f, 0.f};
  f32x4 Oc0 = ZERO4, Oc1 = ZERO4, lacc = ZERO4;
  float mrun = -INFINITY;

  f16x8 ones;
#pragma unroll
  for (int i = 0; i < 8; ++i) ones[i] = (_Float16)1.0f;

  // double-buffered K fragments (static names; rule #20)
  f16x8 kfA0, kfA1, kfA2, kfA3, kfB0, kfB1, kfB2, kfB3;
#define LOADK(dst0, dst1, dst2, dst3, kvarg)                                  \
  {                                                                           \
    const u16* kb = Kp + (size_t)((kvarg) + r) * 32 + g * 8;                  \
    dst0 = *(const f16x8*)(kb);                                               \
    dst1 = *(const f16x8*)(kb + 16 * 32);                                     \
    dst2 = *(const f16x8*)(kb + 32 * 32);                                     \
    dst3 = *(const f16x8*)(kb + 48 * 32);                                     \
  }

  LOADK(kfA0, kfA1, kfA2, kfA3, 0);

// NOTE: internal var is `kvt` (NOT kv0) — callers pass expressions involving
// the loop's kv0; an internal `kv0` would self-shadow and read garbage (the
// Round-3 NaN bug).
#define PROCESS(k0, k1, k2, k3, KVB, PREFETCH)                                \
  {                                                                           \
    const int kvt = (KVB);                                                    \
    /* QK^T: 4 MFMA */                                                        \
    f32x4 S0 = MFMA_F16(k0, qf, ZERO4);                                       \
    f32x4 S1 = MFMA_F16(k1, qf, ZERO4);                                       \
    f32x4 S2 = MFMA_F16(k2, qf, ZERO4);                                       \
    f32x4 S3 = MFMA_F16(k3, qf, ZERO4);                                       \
    /* V fragments (permuted layout -> contiguous 16B) */                     \
    const u16* vb = Vp + (size_t)r * NSP + kvt + g * 8;                       \
    const f16x8 vf00 = *(const f16x8*)(vb);                                   \
    const f16x8 vf01 = *(const f16x8*)(vb + 32);                              \
    const f16x8 vf10 = *(const f16x8*)(vb + 16 * NSP);                        \
    const f16x8 vf11 = *(const f16x8*)(vb + 16 * NSP + 32);                   \
    PREFETCH;                                                                 \
    /* row max over 16 in-lane + cross-g */                                   \
    float t0 = fmaxf(fmaxf(S0[0], S0[1]), fmaxf(S0[2], S0[3]));               \
    float t1 = fmaxf(fmaxf(S1[0], S1[1]), fmaxf(S1[2], S1[3]));               \
    float t2 = fmaxf(fmaxf(S2[0], S2[1]), fmaxf(S2[2], S2[3]));               \
    float t3 = fmaxf(fmaxf(S3[0], S3[1]), fmaxf(S3[2], S3[3]));               \
    float tm = fmaxf(fmaxf(t0, t1), fmaxf(t2, t3));                           \
    tm = fmaxf(tm, __shfl_xor(tm, 16));                                       \
    tm = fmaxf(tm, __shfl_xor(tm, 32));                                       \
    /* T13 defer-max: rescale only when tile max grows past mrun+8 */         \
    if (!__all(tm <= mrun + 8.0f)) {                                          \
      const float nm = fmaxf(mrun, tm);                                       \
      const float al = fexp2(mrun - nm);                                      \
      mrun = nm;                                                              \
      Oc0[0] *= al; Oc0[1] *= al; Oc0[2] *= al; Oc0[3] *= al;                 \
      Oc1[0] *= al; Oc1[1] *= al; Oc1[2] *= al; Oc1[3] *= al;                 \
      lacc[0] *= al; lacc[1] *= al; lacc[2] *= al; lacc[3] *= al;             \
    }                                                                         \
    /* P = exp2(S - mrun), pack to f16 in-lane */                             \
    u32x4 w0, w1;                                                             \
    w0[0] = pk_f16(fexp2(S0[0] - mrun), fexp2(S0[1] - mrun));                 \
    w0[1] = pk_f16(fexp2(S0[2] - mrun), fexp2(S0[3] - mrun));                 \
    w0[2] = pk_f16(fexp2(S1[0] - mrun), fexp2(S1[1] - mrun));                 \
    w0[3] = pk_f16(fexp2(S1[2] - mrun), fexp2(S1[3] - mrun));                 \
    w1[0] = pk_f16(fexp2(S2[0] - mrun), fexp2(S2[1] - mrun));                 \
    w1[1] = pk_f16(fexp2(S2[2] - mrun), fexp2(S2[3] - mrun));                 \
    w1[2] = pk_f16(fexp2(S3[0] - mrun), fexp2(S3[1] - mrun));                 \
    w1[3] = pk_f16(fexp2(S3[2] - mrun), fexp2(S3[3] - mrun));                 \
    const f16x8 pB0 = __builtin_bit_cast(f16x8, w0);                          \
    const f16x8 pB1 = __builtin_bit_cast(f16x8, w1);                          \
    /* PV + row-sum: 6 MFMA */                                                \
    Oc0 = MFMA_F16(vf00, pB0, Oc0);                                           \
    Oc1 = MFMA_F16(vf10, pB0, Oc1);                                           \
    lacc = MFMA_F16(ones, pB0, lacc);                                         \
    Oc0 = MFMA_F16(vf01, pB1, Oc0);                                           \
    Oc1 = MFMA_F16(vf11, pB1, Oc1);                                           \
    lacc = MFMA_F16(ones, pB1, lacc);                                         \
  }

  for (int t = 0; t < 64; t += 2) {
    const int kv0 = t * 64;
    PROCESS(kfA0, kfA1, kfA2, kfA3, kv0,
            LOADK(kfB0, kfB1, kfB2, kfB3, kv0 + 64));
    if (t + 2 < 64) {
      PROCESS(kfB0, kfB1, kfB2, kfB3, kv0 + 64,
              LOADK(kfA0, kfA1, kfA2, kfA3, kv0 + 128));
    } else {
      PROCESS(kfB0, kfB1, kfB2, kfB3, kv0 + 64, );
    }
  }
#undef PROCESS
#undef LOADK

  // epilogue: lane (g,r) holds O[dv = dn*16+g*4+i][q = q0+r]; l = lacc[0]
  const int b = bh >> 2, h = bh & 3;
  const float inv = 1.0f / lacc[0];
  const int q = q0 + r;
  f32x4 o0 = Oc0, o1 = Oc1;
#pragma unroll
  for (int i = 0; i < 4; ++i) { o0[i] *= inv; o1[i] *= inv; }
  float* ab = att + ((size_t)(b * NSP + q)) * 128 + h * 32 + g * 4;
  *(f32x4*)(ab) = o0;
  *(f32x4*)(ab + 16) = o1;
}

// ---------------------------------------------------------------------------
// Kernel C: output projection, fp32 VALU (keeps final stage exact).
// out[b][o][j] = bout[o] + sum_ch Wout[o][ch] * att[b][j][ch]
// grid (64 j-tiles, 2 o-halves, 4 b) x 256 threads; lanes = j (coalesced).
// ---------------------------------------------------------------------------
__global__ __launch_bounds__(256) void outproj_kernel(
    const float* __restrict__ att, const float* __restrict__ Wout,
    const float* __restrict__ bout, float* __restrict__ out)
{
  __shared__ float a_lds[64][129];   // pitch 129: conflict-free per-lane rows
  const int j0    = blockIdx.x * 64;
  const int ohalf = blockIdx.y;
  const int b     = blockIdx.z;
  const int tid   = threadIdx.x;

#pragma unroll
  for (int rep = 0; rep < 8; ++rep) {
    const int idx = tid + rep * 256;
    const int jj = idx >> 5;
    const int cc = (idx & 31) * 4;
    const float4 v = *(const float4*)(att + ((size_t)(b * NSP + j0 + jj)) * 128 + cc);
    a_lds[jj][cc + 0] = v.x;
    a_lds[jj][cc + 1] = v.y;
    a_lds[jj][cc + 2] = v.z;
    a_lds[jj][cc + 3] = v.w;
  }
  __syncthreads();

  const int lane = tid & 63;
  const int wv = __builtin_amdgcn_readfirstlane(tid >> 6);  // force SGPR
  const int o0 = ohalf * 128 + wv * 32;
  const int j = j0 + lane;

#pragma unroll
  for (int og = 0; og < 4; ++og) {
    const int ob = o0 + og * 8;
    float acc[8];
#pragma unroll
    for (int oo = 0; oo < 8; ++oo) acc[oo] = bout[ob + oo];
    for (int ch = 0; ch < 128; ch += 4) {
#pragma unroll
      for (int c2 = 0; c2 < 4; ++c2) {
        const float a = a_lds[lane][ch + c2];
#pragma unroll
        for (int oo = 0; oo < 8; ++oo)
          acc[oo] = fmaf(Wout[(ob + oo) * 128 + ch + c2], a, acc[oo]);
      }
    }
#pragma unroll
    for (int oo = 0; oo < 8; ++oo)
      out[((size_t)(b * 256 + ob + oo)) * NSP + j] = acc[oo];
  }
}

// ---------------------------------------------------------------------------
extern "C" void kernel_launch(void* const* d_in, const int* in_sizes, int n_in,
                              void* d_out, int out_size, void* d_ws, size_t ws_size,
                              hipStream_t stream) {
  const float* x    = (const float*)d_in[0];
  const float* Wq   = (const float*)d_in[1];
  const float* Wk   = (const float*)d_in[2];
  const float* Wv   = (const float*)d_in[3];
  const float* Wout = (const float*)d_in[4];
  const float* bout = (const float*)d_in[5];
  float* out = (float*)d_out;

  // workspace layout (20 MiB total)
  char* ws = (char*)d_ws;
  u16*   Qw  = (u16*)(ws);                    // 4 MiB  [16][4096][32] f16
  u16*   Kw  = (u16*)(ws + (4u << 20));       // 4 MiB  [16][4096][32] f16
  u16*   Vw  = (u16*)(ws + (8u << 20));       // 4 MiB  [16][32][4096] f16 (perm)
  float* att = (float*)(ws + (12u << 20));    // 8 MiB  [4][4096][128] f32

  qkv_proj_kernel<<<dim3(64, 4), 512, 0, stream>>>(x, Wq, Wk, Wv, Qw, Kw, Vw);
  attn_kernel<<<dim3(1024), 256, 0, stream>>>(Qw, Kw, Vw, att);
  outproj_kernel<<<dim3(64, 2, 4), 256, 0, stream>>>(att, Wout, bout, out);
}

// Round 5
// 198.311 us; speedup vs baseline: 1.1932x; 1.1932x over previous
//
#include <hip/hip_runtime.h>
#include <hip/hip_fp16.h>
#include <math.h>

typedef _Float16 f16x8 __attribute__((ext_vector_type(8)));
typedef float    f32x4 __attribute__((ext_vector_type(4)));
typedef unsigned int u32x4 __attribute__((ext_vector_type(4)));
typedef unsigned short u16;
typedef unsigned int   u32;

#define MFMA_F16(a, b, c) __builtin_amdgcn_mfma_f32_16x16x32_f16((a), (b), (c), 0, 0, 0)

#define NSP 4096
// (1/sqrt(32)) * log2(e): fold softmax scale and exp2 conversion into Q
#define QK_SCALE (0.17677669529663687f * 1.4426950408889634f)

__device__ __forceinline__ float fexp2(float x) {
#if __has_builtin(__builtin_amdgcn_exp2f)
  return __builtin_amdgcn_exp2f(x);
#else
  return exp2f(x);
#endif
}

__device__ __forceinline__ u32 pk_f16(float a, float b) {
#if __has_builtin(__builtin_amdgcn_cvt_pkrtz)
  return __builtin_bit_cast(u32, __builtin_amdgcn_cvt_pkrtz(a, b));
#else
  u16 lo = __builtin_bit_cast(u16, (_Float16)a);
  u16 hi = __builtin_bit_cast(u16, (_Float16)b);
  return (u32)lo | ((u32)hi << 16);
#endif
}

__device__ __forceinline__ u16 f16bits(float a) {
  return __builtin_bit_cast(u16, (_Float16)a);
}

__device__ __forceinline__ float f16val(u16 v) {
  return (float)__builtin_bit_cast(_Float16, v);
}

// ---------------------------------------------------------------------------
// Kernel A: QKV projection (unchanged from round 4, it passed).
// Q,K stored [bh][n][32] f16 (Q pre-scaled by QK_SCALE); V stored transposed
// [bh][32][n] with per-32-column MFMA k-slot permutation.
// ---------------------------------------------------------------------------
__global__ __launch_bounds__(512) void qkv_proj_kernel(
    const float* __restrict__ x, const float* __restrict__ Wq,
    const float* __restrict__ Wk, const float* __restrict__ Wv,
    u16* __restrict__ Qo, u16* __restrict__ Ko, u16* __restrict__ Vo)
{
  const int b  = blockIdx.y;
  const int j0 = blockIdx.x * 64;
  const int tid  = threadIdx.x;
  const int wave = tid >> 6, lane = tid & 63;
  const int g = lane >> 4, r = lane & 15;
  const float* xb = x + (size_t)b * 256 * NSP;

  const f32x4 ZERO4 = {0.f, 0.f, 0.f, 0.f};
  f32x4 acc[3][4];
#pragma unroll
  for (int m = 0; m < 3; ++m)
#pragma unroll
    for (int n = 0; n < 4; ++n) acc[m][n] = ZERO4;

  for (int kc = 0; kc < 8; ++kc) {
    f16x8 bfrag[4];
#pragma unroll
    for (int nt = 0; nt < 4; ++nt) {
      const float* src = xb + (size_t)(kc * 32 + g * 8) * NSP + j0 + nt * 16 + r;
      f16x8 f;
#pragma unroll
      for (int i = 0; i < 8; ++i) f[i] = (_Float16)src[(size_t)i * NSP];
      bfrag[nt] = f;
    }
#pragma unroll
    for (int mm = 0; mm < 3; ++mm) {
      const int o_tile = wave * 48 + mm * 16;
      const float* wsrc = (o_tile < 128) ? Wq : ((o_tile < 256) ? Wk : Wv);
      const float* arow = wsrc + ((o_tile & 127) + r) * 256 + kc * 32 + g * 8;
      f16x8 af;
#pragma unroll
      for (int i = 0; i < 8; ++i) af[i] = (_Float16)arow[i];
#pragma unroll
      for (int nt = 0; nt < 4; ++nt)
        acc[mm][nt] = MFMA_F16(af, bfrag[nt], acc[mm][nt]);
    }
  }

#pragma unroll
  for (int mm = 0; mm < 3; ++mm) {
    const int o_tile = wave * 48 + mm * 16;
    const int part = o_tile >> 7;            // 0=Q 1=K 2=V
    const int o_in = o_tile & 127;
    const int head = o_in >> 5;
    const int dbase = (o_in & 31) + g * 4;
#pragma unroll
    for (int nt = 0; nt < 4; ++nt) {
      const int j = j0 + nt * 16 + r;
      if (part < 2) {
        u16* dst = (part == 0) ? Qo : Ko;
        const float sc = (part == 0) ? QK_SCALE : 1.0f;
        const size_t base = ((size_t)((b * 4 + head) * NSP + j)) * 32 + dbase;
        const u32 p01 = pk_f16(acc[mm][nt][0] * sc, acc[mm][nt][1] * sc);
        const u32 p23 = pk_f16(acc[mm][nt][2] * sc, acc[mm][nt][3] * sc);
        *(u32*)(dst + base)     = p01;
        *(u32*)(dst + base + 2) = p23;
      } else {
        // permuted V store: within each 32-col block, kv j -> slot s
        const int jb = j & ~31, off = j & 31;
        const int s = (((off >> 2) & 3) << 3) | (((off >> 4) & 1) << 2) | (off & 3);
#pragma unroll
        for (int i = 0; i < 4; ++i)
          Vo[((size_t)((b * 4 + head) * 32 + dbase + i)) * NSP + jb + s] =
              f16bits(acc[mm][nt][i]);
      }
    }
  }
}

// ---------------------------------------------------------------------------
// Kernel B: flash attention, 32 q-rows/wave (2 independent softmax chains for
// ILP), KV-split x2 (occupancy), register-resident P, no LDS, no barriers.
// grid 1024 x 256 thr: d -> bh=(d&7)*2+((d>>3)&1), half=(d>>4)&1, qt=d>>5.
// Partial output (normalized O in f16, m/l in f32) stored INSIDE d_out:
//   u16 view: OU[b*2097152 + s*4096 + q], s=(half*4+h)*32+dv   (f32 o<128)
//   f32 view: F[(b*256 + 128 + (half*4+h)*2 + {0,1})*4096 + q] (m, l)
// outproj merges the two halves before projecting (slab-disjoint, race-free).
// ---------------------------------------------------------------------------
__global__ __launch_bounds__(256, 4) void attn_kernel(
    const u16* __restrict__ Qg, const u16* __restrict__ Kg,
    const u16* __restrict__ Vg, float* __restrict__ outp)
{
  const int d    = blockIdx.x;
  const int bh   = (d & 7) * 2 + ((d >> 3) & 1);   // XCD-local bh pair
  const int half = (d >> 4) & 1;
  const int qt   = d >> 5;                          // 0..31
  const int wave = threadIdx.x >> 6, lane = threadIdx.x & 63;
  const int g = lane >> 4, r = lane & 15;
  const int q0 = qt * 128 + wave * 32;              // this wave: 32 q-rows
  const int kvbase = half * 2048;                   // this block: 2048 kv

  const size_t qkb = (size_t)bh * NSP * 32;
  const u16* Kp = Kg + qkb;                         // [n][32]
  const u16* Vp = Vg + (size_t)bh * 32 * NSP;       // [32][n] permuted

  const f16x8 qf0 = *(const f16x8*)(Qg + qkb + (size_t)(q0 + r) * 32 + g * 8);
  const f16x8 qf1 = *(const f16x8*)(Qg + qkb + (size_t)(q0 + 16 + r) * 32 + g * 8);

  const f32x4 ZERO4 = {0.f, 0.f, 0.f, 0.f};
  f32x4 Oc00 = ZERO4, Oc01 = ZERO4, Oc10 = ZERO4, Oc11 = ZERO4;
  f32x4 lacc0 = ZERO4, lacc1 = ZERO4;
  float mrun0 = -INFINITY, mrun1 = -INFINITY;

  f16x8 ones;
#pragma unroll
  for (int i = 0; i < 8; ++i) ones[i] = (_Float16)1.0f;

  f16x8 kfA0, kfA1, kfA2, kfA3, kfB0, kfB1, kfB2, kfB3;
#define LOADK(d0, d1, d2, d3, kvarg)                                          \
  {                                                                           \
    const u16* kb = Kp + (size_t)((kvarg) + r) * 32 + g * 8;                  \
    d0 = *(const f16x8*)(kb);                                                 \
    d1 = *(const f16x8*)(kb + 16 * 32);                                       \
    d2 = *(const f16x8*)(kb + 32 * 32);                                       \
    d3 = *(const f16x8*)(kb + 48 * 32);                                       \
  }

  LOADK(kfA0, kfA1, kfA2, kfA3, kvbase);

// internal var is kvt (NOT kv0/kvl) — callers pass expressions in kvl;
// self-shadow here was the round-3 NaN bug.
#define PROCESS(K0, K1, K2, K3, KVT, PREFETCH)                                \
  {                                                                           \
    const int kvt = (KVT);                                                    \
    /* V loads + K prefetch issued first: ~400cy ahead of their use */        \
    const u16* vb = Vp + (size_t)r * NSP + kvt + g * 8;                       \
    const f16x8 vf00 = *(const f16x8*)(vb);                                   \
    const f16x8 vf01 = *(const f16x8*)(vb + 32);                              \
    const f16x8 vf10 = *(const f16x8*)(vb + 16 * NSP);                        \
    const f16x8 vf11 = *(const f16x8*)(vb + 16 * NSP + 32);                   \
    PREFETCH;                                                                 \
    /* QK^T: 8 MFMAs, two independent chains */                               \
    f32x4 S00 = MFMA_F16(K0, qf0, ZERO4);                                     \
    f32x4 S01 = MFMA_F16(K1, qf0, ZERO4);                                     \
    f32x4 S02 = MFMA_F16(K2, qf0, ZERO4);                                     \
    f32x4 S03 = MFMA_F16(K3, qf0, ZERO4);                                     \
    f32x4 S10 = MFMA_F16(K0, qf1, ZERO4);                                     \
    f32x4 S11 = MFMA_F16(K1, qf1, ZERO4);                                     \
    f32x4 S12 = MFMA_F16(K2, qf1, ZERO4);                                     \
    f32x4 S13 = MFMA_F16(K3, qf1, ZERO4);                                     \
    float tm0 = fmaxf(                                                        \
        fmaxf(fmaxf(fmaxf(S00[0], S00[1]), fmaxf(S00[2], S00[3])),            \
              fmaxf(fmaxf(S01[0], S01[1]), fmaxf(S01[2], S01[3]))),           \
        fmaxf(fmaxf(fmaxf(S02[0], S02[1]), fmaxf(S02[2], S02[3])),            \
              fmaxf(fmaxf(S03[0], S03[1]), fmaxf(S03[2], S03[3]))));          \
    float tm1 = fmaxf(                                                        \
        fmaxf(fmaxf(fmaxf(S10[0], S10[1]), fmaxf(S10[2], S10[3])),            \
              fmaxf(fmaxf(S11[0], S11[1]), fmaxf(S11[2], S11[3]))),           \
        fmaxf(fmaxf(fmaxf(S12[0], S12[1]), fmaxf(S12[2], S12[3])),            \
              fmaxf(fmaxf(S13[0], S13[1]), fmaxf(S13[2], S13[3]))));          \
    tm0 = fmaxf(tm0, __shfl_xor(tm0, 16));                                    \
    tm0 = fmaxf(tm0, __shfl_xor(tm0, 32));                                    \
    tm1 = fmaxf(tm1, __shfl_xor(tm1, 16));                                    \
    tm1 = fmaxf(tm1, __shfl_xor(tm1, 32));                                    \
    /* T13 defer-max, one combined wave-uniform branch */                     \
    if (__any((tm0 > mrun0 + 8.0f) || (tm1 > mrun1 + 8.0f))) {                \
      const float nm0 = fmaxf(mrun0, tm0);                                    \
      const float al0 = fexp2(mrun0 - nm0);                                   \
      mrun0 = nm0;                                                            \
      const float nm1 = fmaxf(mrun1, tm1);                                    \
      const float al1 = fexp2(mrun1 - nm1);                                   \
      mrun1 = nm1;                                                            \
      Oc00[0] *= al0; Oc00[1] *= al0; Oc00[2] *= al0; Oc00[3] *= al0;         \
      Oc01[0] *= al0; Oc01[1] *= al0; Oc01[2] *= al0; Oc01[3] *= al0;         \
      lacc0[0] *= al0;                                                        \
      Oc10[0] *= al1; Oc10[1] *= al1; Oc10[2] *= al1; Oc10[3] *= al1;         \
      Oc11[0] *= al1; Oc11[1] *= al1; Oc11[2] *= al1; Oc11[3] *= al1;         \
      lacc1[0] *= al1;                                                        \
    }                                                                         \
    u32x4 w0, w1, w2, w3;                                                     \
    w0[0] = pk_f16(fexp2(S00[0] - mrun0), fexp2(S00[1] - mrun0));             \
    w0[1] = pk_f16(fexp2(S00[2] - mrun0), fexp2(S00[3] - mrun0));             \
    w0[2] = pk_f16(fexp2(S01[0] - mrun0), fexp2(S01[1] - mrun0));             \
    w0[3] = pk_f16(fexp2(S01[2] - mrun0), fexp2(S01[3] - mrun0));             \
    w1[0] = pk_f16(fexp2(S02[0] - mrun0), fexp2(S02[1] - mrun0));             \
    w1[1] = pk_f16(fexp2(S02[2] - mrun0), fexp2(S02[3] - mrun0));             \
    w1[2] = pk_f16(fexp2(S03[0] - mrun0), fexp2(S03[1] - mrun0));             \
    w1[3] = pk_f16(fexp2(S03[2] - mrun0), fexp2(S03[3] - mrun0));             \
    w2[0] = pk_f16(fexp2(S10[0] - mrun1), fexp2(S10[1] - mrun1));             \
    w2[1] = pk_f16(fexp2(S10[2] - mrun1), fexp2(S10[3] - mrun1));             \
    w2[2] = pk_f16(fexp2(S11[0] - mrun1), fexp2(S11[1] - mrun1));             \
    w2[3] = pk_f16(fexp2(S11[2] - mrun1), fexp2(S11[3] - mrun1));             \
    w3[0] = pk_f16(fexp2(S12[0] - mrun1), fexp2(S12[1] - mrun1));             \
    w3[1] = pk_f16(fexp2(S12[2] - mrun1), fexp2(S12[3] - mrun1));             \
    w3[2] = pk_f16(fexp2(S13[0] - mrun1), fexp2(S13[1] - mrun1));             \
    w3[3] = pk_f16(fexp2(S13[2] - mrun1), fexp2(S13[3] - mrun1));             \
    const f16x8 pB00 = __builtin_bit_cast(f16x8, w0);                         \
    const f16x8 pB01 = __builtin_bit_cast(f16x8, w1);                         \
    const f16x8 pB10 = __builtin_bit_cast(f16x8, w2);                         \
    const f16x8 pB11 = __builtin_bit_cast(f16x8, w3);                         \
    /* PV + row-sums: 12 MFMAs */                                             \
    Oc00 = MFMA_F16(vf00, pB00, Oc00);                                        \
    Oc01 = MFMA_F16(vf10, pB00, Oc01);                                        \
    lacc0 = MFMA_F16(ones, pB00, lacc0);                                      \
    Oc10 = MFMA_F16(vf00, pB10, Oc10);                                        \
    Oc11 = MFMA_F16(vf10, pB10, Oc11);                                        \
    lacc1 = MFMA_F16(ones, pB10, lacc1);                                      \
    Oc00 = MFMA_F16(vf01, pB01, Oc00);                                        \
    Oc01 = MFMA_F16(vf11, pB01, Oc01);                                        \
    lacc0 = MFMA_F16(ones, pB01, lacc0);                                      \
    Oc10 = MFMA_F16(vf01, pB11, Oc10);                                        \
    Oc11 = MFMA_F16(vf11, pB11, Oc11);                                        \
    lacc1 = MFMA_F16(ones, pB11, lacc1);                                      \
  }

  for (int tt = 0; tt < 32; tt += 2) {
    const int kvl = kvbase + tt * 64;
    PROCESS(kfA0, kfA1, kfA2, kfA3, kvl,
            LOADK(kfB0, kfB1, kfB2, kfB3, kvl + 64));
    if (tt + 2 < 32) {
      PROCESS(kfB0, kfB1, kfB2, kfB3, kvl + 64,
              LOADK(kfA0, kfA1, kfA2, kfA3, kvl + 128));
    } else {
      PROCESS(kfB0, kfB1, kfB2, kfB3, kvl + 64, );
    }
  }
#undef PROCESS
#undef LOADK

  // epilogue: partials into d_out (normalized O f16; m,l f32)
  const int b = bh >> 2, h = bh & 3;
  u16* OU = (u16*)outp;
  const size_t ob16 =
      (size_t)b * 2097152 + (size_t)((half * 4 + h) * 32) * 4096;

  {
    const float l0 = lacc0[0], inv0 = 1.0f / l0;
    const int q = q0 + r;
#pragma unroll
    for (int i = 0; i < 4; ++i) {
      OU[ob16 + (size_t)(g * 4 + i) * 4096 + q]      = f16bits(Oc00[i] * inv0);
      OU[ob16 + (size_t)(16 + g * 4 + i) * 4096 + q] = f16bits(Oc01[i] * inv0);
    }
    if (g == 0) {
      const size_t mlb =
          ((size_t)(b * 256 + 128 + (half * 4 + h) * 2)) * 4096 + q;
      outp[mlb] = mrun0;
      outp[mlb + 4096] = l0;
    }
  }
  {
    const float l1 = lacc1[0], inv1 = 1.0f / l1;
    const int q = q0 + 16 + r;
#pragma unroll
    for (int i = 0; i < 4; ++i) {
      OU[ob16 + (size_t)(g * 4 + i) * 4096 + q]      = f16bits(Oc10[i] * inv1);
      OU[ob16 + (size_t)(16 + g * 4 + i) * 4096 + q] = f16bits(Oc11[i] * inv1);
    }
    if (g == 0) {
      const size_t mlb =
          ((size_t)(b * 256 + 128 + (half * 4 + h) * 2)) * 4096 + q;
      outp[mlb] = mrun1;
      outp[mlb + 4096] = l1;
    }
  }
}

// ---------------------------------------------------------------------------
// Kernel C: merge KV-split partials + output projection (fp32 VALU).
// grid (64 j-tiles, 4 b) x 512 threads. Reads partials from d_out (slab-
// disjoint per block), merges into LDS, __syncthreads, then GEMM overwrites
// the slab. Each wave handles 32 output channels.
// ---------------------------------------------------------------------------
__global__ __launch_bounds__(512) void outproj_kernel(
    const float* __restrict__ Wout, const float* __restrict__ bout,
    float* __restrict__ out)
{
  __shared__ float a_lds[64][129];
  const int j0  = blockIdx.x * 64;
  const int b   = blockIdx.y;
  const int tid = threadIdx.x;
  const int jl  = tid & 63;
  const int grp = tid >> 6;          // 0..7
  const int h   = grp & 3;
  const int dup = grp >> 2;          // d-half: 0 -> d 0..15, 1 -> d 16..31
  const int j   = j0 + jl;

  // merge weights for (b, j, h)
  const size_t mlb0 = ((size_t)(b * 256 + 128 + h * 2)) * 4096 + j;       // half 0
  const size_t mlb1 = ((size_t)(b * 256 + 128 + 8 + h * 2)) * 4096 + j;   // half 1
  const float m_a = out[mlb0], l_a = out[mlb0 + 4096];
  const float m_b = out[mlb1], l_b = out[mlb1 + 4096];
  const float M = fmaxf(m_a, m_b);
  float w_a = l_a * fexp2(m_a - M);
  float w_b = l_b * fexp2(m_b - M);
  const float winv = 1.0f / (w_a + w_b);
  w_a *= winv; w_b *= winv;

  const u16* OU = (const u16*)out;
  const size_t ob16 = (size_t)b * 2097152;
#pragma unroll
  for (int k = 0; k < 16; ++k) {
    const int dd = dup * 16 + k;
    const int ch = h * 32 + dd;
    const float oa = f16val(OU[ob16 + (size_t)ch * 4096 + j]);
    const float obv = f16val(OU[ob16 + (size_t)(128 + ch) * 4096 + j]);
    a_lds[jl][ch] = w_a * oa + w_b * obv;
  }
  __syncthreads();

  const int o0 = grp * 32;
#pragma unroll
  for (int og = 0; og < 4; ++og) {
    const int ob8 = o0 + og * 8;
    float acc[8];
#pragma unroll
    for (int oo = 0; oo < 8; ++oo) acc[oo] = bout[ob8 + oo];
    for (int ch = 0; ch < 128; ch += 4) {
#pragma unroll
      for (int c2 = 0; c2 < 4; ++c2) {
        const float a = a_lds[jl][ch + c2];
#pragma unroll
        for (int oo = 0; oo < 8; ++oo)
          acc[oo] = fmaf(Wout[(ob8 + oo) * 128 + ch + c2], a, acc[oo]);
      }
    }
#pragma unroll
    for (int oo = 0; oo < 8; ++oo)
      out[((size_t)(b * 256 + ob8 + oo)) * 4096 + j] = acc[oo];
  }
}

// ---------------------------------------------------------------------------
extern "C" void kernel_launch(void* const* d_in, const int* in_sizes, int n_in,
                              void* d_out, int out_size, void* d_ws, size_t ws_size,
                              hipStream_t stream) {
  const float* x    = (const float*)d_in[0];
  const float* Wq   = (const float*)d_in[1];
  const float* Wk   = (const float*)d_in[2];
  const float* Wv   = (const float*)d_in[3];
  const float* Wout = (const float*)d_in[4];
  const float* bout = (const float*)d_in[5];
  float* out = (float*)d_out;

  // workspace: 12 MiB (partials live inside d_out)
  char* ws = (char*)d_ws;
  u16* Qw = (u16*)(ws);                 // 4 MiB  [16][4096][32] f16
  u16* Kw = (u16*)(ws + (4u << 20));    // 4 MiB  [16][4096][32] f16
  u16* Vw = (u16*)(ws + (8u << 20));    // 4 MiB  [16][32][4096] f16 (perm)

  qkv_proj_kernel<<<dim3(64, 4), 512, 0, stream>>>(x, Wq, Wk, Wv, Qw, Kw, Vw);
  attn_kernel<<<dim3(1024), 256, 0, stream>>>(Qw, Kw, Vw, out);
  outproj_kernel<<<dim3(64, 4), 512, 0, stream>>>(Wout, bout, out);
}

// Round 6
// 181.614 us; speedup vs baseline: 1.3029x; 1.0919x over previous
//
#include <hip/hip_runtime.h>
#include <hip/hip_fp16.h>
#include <math.h>

typedef _Float16 f16x8 __attribute__((ext_vector_type(8)));
typedef float    f32x4 __attribute__((ext_vector_type(4)));
typedef unsigned int u32x4 __attribute__((ext_vector_type(4)));
typedef unsigned short u16;
typedef unsigned int   u32;

#define MFMA_F16(a, b, c) __builtin_amdgcn_mfma_f32_16x16x32_f16((a), (b), (c), 0, 0, 0)

#define NSP 4096
// (1/sqrt(32)) * log2(e): fold softmax scale and exp2 conversion into Q
#define QK_SCALE (0.17677669529663687f * 1.4426950408889634f)

__device__ __forceinline__ float fexp2(float x) {
#if __has_builtin(__builtin_amdgcn_exp2f)
  return __builtin_amdgcn_exp2f(x);
#else
  return exp2f(x);
#endif
}

__device__ __forceinline__ u32 pk_f16(float a, float b) {
#if __has_builtin(__builtin_amdgcn_cvt_pkrtz)
  return __builtin_bit_cast(u32, __builtin_amdgcn_cvt_pkrtz(a, b));
#else
  u16 lo = __builtin_bit_cast(u16, (_Float16)a);
  u16 hi = __builtin_bit_cast(u16, (_Float16)b);
  return (u32)lo | ((u32)hi << 16);
#endif
}

__device__ __forceinline__ u16 f16bits(float a) {
  return __builtin_bit_cast(u16, (_Float16)a);
}

__device__ __forceinline__ float f16val(u16 v) {
  return (float)__builtin_bit_cast(_Float16, v);
}

// ---------------------------------------------------------------------------
// Kernel A: QKV projection (unchanged).
// Q,K stored [bh][n][32] f16 (Q pre-scaled by QK_SCALE); V stored transposed
// [bh][32][n] with per-32-column MFMA k-slot permutation.
// ---------------------------------------------------------------------------
__global__ __launch_bounds__(512) void qkv_proj_kernel(
    const float* __restrict__ x, const float* __restrict__ Wq,
    const float* __restrict__ Wk, const float* __restrict__ Wv,
    u16* __restrict__ Qo, u16* __restrict__ Ko, u16* __restrict__ Vo)
{
  const int b  = blockIdx.y;
  const int j0 = blockIdx.x * 64;
  const int tid  = threadIdx.x;
  const int wave = tid >> 6, lane = tid & 63;
  const int g = lane >> 4, r = lane & 15;
  const float* xb = x + (size_t)b * 256 * NSP;

  const f32x4 ZERO4 = {0.f, 0.f, 0.f, 0.f};
  f32x4 acc[3][4];
#pragma unroll
  for (int m = 0; m < 3; ++m)
#pragma unroll
    for (int n = 0; n < 4; ++n) acc[m][n] = ZERO4;

  for (int kc = 0; kc < 8; ++kc) {
    f16x8 bfrag[4];
#pragma unroll
    for (int nt = 0; nt < 4; ++nt) {
      const float* src = xb + (size_t)(kc * 32 + g * 8) * NSP + j0 + nt * 16 + r;
      f16x8 f;
#pragma unroll
      for (int i = 0; i < 8; ++i) f[i] = (_Float16)src[(size_t)i * NSP];
      bfrag[nt] = f;
    }
#pragma unroll
    for (int mm = 0; mm < 3; ++mm) {
      const int o_tile = wave * 48 + mm * 16;
      const float* wsrc = (o_tile < 128) ? Wq : ((o_tile < 256) ? Wk : Wv);
      const float* arow = wsrc + ((o_tile & 127) + r) * 256 + kc * 32 + g * 8;
      f16x8 af;
#pragma unroll
      for (int i = 0; i < 8; ++i) af[i] = (_Float16)arow[i];
#pragma unroll
      for (int nt = 0; nt < 4; ++nt)
        acc[mm][nt] = MFMA_F16(af, bfrag[nt], acc[mm][nt]);
    }
  }

#pragma unroll
  for (int mm = 0; mm < 3; ++mm) {
    const int o_tile = wave * 48 + mm * 16;
    const int part = o_tile >> 7;            // 0=Q 1=K 2=V
    const int o_in = o_tile & 127;
    const int head = o_in >> 5;
    const int dbase = (o_in & 31) + g * 4;
#pragma unroll
    for (int nt = 0; nt < 4; ++nt) {
      const int j = j0 + nt * 16 + r;
      if (part < 2) {
        u16* dst = (part == 0) ? Qo : Ko;
        const float sc = (part == 0) ? QK_SCALE : 1.0f;
        const size_t base = ((size_t)((b * 4 + head) * NSP + j)) * 32 + dbase;
        const u32 p01 = pk_f16(acc[mm][nt][0] * sc, acc[mm][nt][1] * sc);
        const u32 p23 = pk_f16(acc[mm][nt][2] * sc, acc[mm][nt][3] * sc);
        *(u32*)(dst + base)     = p01;
        *(u32*)(dst + base + 2) = p23;
      } else {
        // permuted V store: within each 32-col block, kv j -> slot s
        const int jb = j & ~31, off = j & 31;
        const int s = (((off >> 2) & 3) << 3) | (((off >> 4) & 1) << 2) | (off & 3);
#pragma unroll
        for (int i = 0; i < 4; ++i)
          Vo[((size_t)((b * 4 + head) * 32 + dbase + i)) * NSP + jb + s] =
              f16bits(acc[mm][nt][i]);
      }
    }
  }
}

// ---------------------------------------------------------------------------
// Kernel B: flash attention, 32 q-rows/wave (2 independent softmax chains),
// KV-split x2, register-resident P, no LDS, no barriers.
// ROUND 6 CHANGE: __launch_bounds__(256, 3) — the (256,4) VGPR cap of 128
// forced ~90MB of scratch spill traffic (round-5 counters: WRITE_SIZE 98MB
// vs 9MB of real output, VGPR_Count 64). Cap is now ~168 regs; peak liveness
// estimate ~140.
// ---------------------------------------------------------------------------
__global__ __launch_bounds__(256, 3) void attn_kernel(
    const u16* __restrict__ Qg, const u16* __restrict__ Kg,
    const u16* __restrict__ Vg, float* __restrict__ outp)
{
  const int d    = blockIdx.x;
  const int bh   = (d & 7) * 2 + ((d >> 3) & 1);   // XCD-local bh pair
  const int half = (d >> 4) & 1;
  const int qt   = d >> 5;                          // 0..31
  const int wave = threadIdx.x >> 6, lane = threadIdx.x & 63;
  const int g = lane >> 4, r = lane & 15;
  const int q0 = qt * 128 + wave * 32;              // this wave: 32 q-rows
  const int kvbase = half * 2048;                   // this block: 2048 kv

  const size_t qkb = (size_t)bh * NSP * 32;
  const u16* Kp = Kg + qkb;                         // [n][32]
  const u16* Vp = Vg + (size_t)bh * 32 * NSP;       // [32][n] permuted

  const f16x8 qf0 = *(const f16x8*)(Qg + qkb + (size_t)(q0 + r) * 32 + g * 8);
  const f16x8 qf1 = *(const f16x8*)(Qg + qkb + (size_t)(q0 + 16 + r) * 32 + g * 8);

  const f32x4 ZERO4 = {0.f, 0.f, 0.f, 0.f};
  f32x4 Oc00 = ZERO4, Oc01 = ZERO4, Oc10 = ZERO4, Oc11 = ZERO4;
  f32x4 lacc0 = ZERO4, lacc1 = ZERO4;
  float mrun0 = -INFINITY, mrun1 = -INFINITY;

  f16x8 ones;
#pragma unroll
  for (int i = 0; i < 8; ++i) ones[i] = (_Float16)1.0f;

  f16x8 kfA0, kfA1, kfA2, kfA3, kfB0, kfB1, kfB2, kfB3;
#define LOADK(d0, d1, d2, d3, kvarg)                                          \
  {                                                                           \
    const u16* kb = Kp + (size_t)((kvarg) + r) * 32 + g * 8;                  \
    d0 = *(const f16x8*)(kb);                                                 \
    d1 = *(const f16x8*)(kb + 16 * 32);                                       \
    d2 = *(const f16x8*)(kb + 32 * 32);                                       \
    d3 = *(const f16x8*)(kb + 48 * 32);                                       \
  }

  LOADK(kfA0, kfA1, kfA2, kfA3, kvbase);

// internal var is kvt (NOT kv0/kvl) — callers pass expressions in kvl;
// self-shadow here was the round-3 NaN bug.
#define PROCESS(K0, K1, K2, K3, KVT, PREFETCH)                                \
  {                                                                           \
    const int kvt = (KVT);                                                    \
    /* V loads + K prefetch issued first: ~400cy ahead of their use */        \
    const u16* vb = Vp + (size_t)r * NSP + kvt + g * 8;                       \
    const f16x8 vf00 = *(const f16x8*)(vb);                                   \
    const f16x8 vf01 = *(const f16x8*)(vb + 32);                              \
    const f16x8 vf10 = *(const f16x8*)(vb + 16 * NSP);                        \
    const f16x8 vf11 = *(const f16x8*)(vb + 16 * NSP + 32);                   \
    PREFETCH;                                                                 \
    /* QK^T: 8 MFMAs, two independent chains */                               \
    f32x4 S00 = MFMA_F16(K0, qf0, ZERO4);                                     \
    f32x4 S01 = MFMA_F16(K1, qf0, ZERO4);                                     \
    f32x4 S02 = MFMA_F16(K2, qf0, ZERO4);                                     \
    f32x4 S03 = MFMA_F16(K3, qf0, ZERO4);                                     \
    f32x4 S10 = MFMA_F16(K0, qf1, ZERO4);                                     \
    f32x4 S11 = MFMA_F16(K1, qf1, ZERO4);                                     \
    f32x4 S12 = MFMA_F16(K2, qf1, ZERO4);                                     \
    f32x4 S13 = MFMA_F16(K3, qf1, ZERO4);                                     \
    float tm0 = fmaxf(                                                        \
        fmaxf(fmaxf(fmaxf(S00[0], S00[1]), fmaxf(S00[2], S00[3])),            \
              fmaxf(fmaxf(S01[0], S01[1]), fmaxf(S01[2], S01[3]))),           \
        fmaxf(fmaxf(fmaxf(S02[0], S02[1]), fmaxf(S02[2], S02[3])),            \
              fmaxf(fmaxf(S03[0], S03[1]), fmaxf(S03[2], S03[3]))));          \
    float tm1 = fmaxf(                                                        \
        fmaxf(fmaxf(fmaxf(S10[0], S10[1]), fmaxf(S10[2], S10[3])),            \
              fmaxf(fmaxf(S11[0], S11[1]), fmaxf(S11[2], S11[3]))),           \
        fmaxf(fmaxf(fmaxf(S12[0], S12[1]), fmaxf(S12[2], S12[3])),            \
              fmaxf(fmaxf(S13[0], S13[1]), fmaxf(S13[2], S13[3]))));          \
    tm0 = fmaxf(tm0, __shfl_xor(tm0, 16));                                    \
    tm0 = fmaxf(tm0, __shfl_xor(tm0, 32));                                    \
    tm1 = fmaxf(tm1, __shfl_xor(tm1, 16));                                    \
    tm1 = fmaxf(tm1, __shfl_xor(tm1, 32));                                    \
    /* T13 defer-max, one combined wave-uniform branch */                     \
    if (__any((tm0 > mrun0 + 8.0f) || (tm1 > mrun1 + 8.0f))) {                \
      const float nm0 = fmaxf(mrun0, tm0);                                    \
      const float al0 = fexp2(mrun0 - nm0);                                   \
      mrun0 = nm0;                                                            \
      const float nm1 = fmaxf(mrun1, tm1);                                    \
      const float al1 = fexp2(mrun1 - nm1);                                   \
      mrun1 = nm1;                                                            \
      Oc00[0] *= al0; Oc00[1] *= al0; Oc00[2] *= al0; Oc00[3] *= al0;         \
      Oc01[0] *= al0; Oc01[1] *= al0; Oc01[2] *= al0; Oc01[3] *= al0;         \
      lacc0[0] *= al0;                                                        \
      Oc10[0] *= al1; Oc10[1] *= al1; Oc10[2] *= al1; Oc10[3] *= al1;         \
      Oc11[0] *= al1; Oc11[1] *= al1; Oc11[2] *= al1; Oc11[3] *= al1;         \
      lacc1[0] *= al1;                                                        \
    }                                                                         \
    u32x4 w0, w1, w2, w3;                                                     \
    w0[0] = pk_f16(fexp2(S00[0] - mrun0), fexp2(S00[1] - mrun0));             \
    w0[1] = pk_f16(fexp2(S00[2] - mrun0), fexp2(S00[3] - mrun0));             \
    w0[2] = pk_f16(fexp2(S01[0] - mrun0), fexp2(S01[1] - mrun0));             \
    w0[3] = pk_f16(fexp2(S01[2] - mrun0), fexp2(S01[3] - mrun0));             \
    w1[0] = pk_f16(fexp2(S02[0] - mrun0), fexp2(S02[1] - mrun0));             \
    w1[1] = pk_f16(fexp2(S02[2] - mrun0), fexp2(S02[3] - mrun0));             \
    w1[2] = pk_f16(fexp2(S03[0] - mrun0), fexp2(S03[1] - mrun0));             \
    w1[3] = pk_f16(fexp2(S03[2] - mrun0), fexp2(S03[3] - mrun0));             \
    w2[0] = pk_f16(fexp2(S10[0] - mrun1), fexp2(S10[1] - mrun1));             \
    w2[1] = pk_f16(fexp2(S10[2] - mrun1), fexp2(S10[3] - mrun1));             \
    w2[2] = pk_f16(fexp2(S11[0] - mrun1), fexp2(S11[1] - mrun1));             \
    w2[3] = pk_f16(fexp2(S11[2] - mrun1), fexp2(S11[3] - mrun1));             \
    w3[0] = pk_f16(fexp2(S12[0] - mrun1), fexp2(S12[1] - mrun1));             \
    w3[1] = pk_f16(fexp2(S12[2] - mrun1), fexp2(S12[3] - mrun1));             \
    w3[2] = pk_f16(fexp2(S13[0] - mrun1), fexp2(S13[1] - mrun1));             \
    w3[3] = pk_f16(fexp2(S13[2] - mrun1), fexp2(S13[3] - mrun1));             \
    const f16x8 pB00 = __builtin_bit_cast(f16x8, w0);                         \
    const f16x8 pB01 = __builtin_bit_cast(f16x8, w1);                         \
    const f16x8 pB10 = __builtin_bit_cast(f16x8, w2);                         \
    const f16x8 pB11 = __builtin_bit_cast(f16x8, w3);                         \
    /* PV + row-sums: 12 MFMAs */                                             \
    Oc00 = MFMA_F16(vf00, pB00, Oc00);                                        \
    Oc01 = MFMA_F16(vf10, pB00, Oc01);                                        \
    lacc0 = MFMA_F16(ones, pB00, lacc0);                                      \
    Oc10 = MFMA_F16(vf00, pB10, Oc10);                                        \
    Oc11 = MFMA_F16(vf10, pB10, Oc11);                                        \
    lacc1 = MFMA_F16(ones, pB10, lacc1);                                      \
    Oc00 = MFMA_F16(vf01, pB01, Oc00);                                        \
    Oc01 = MFMA_F16(vf11, pB01, Oc01);                                        \
    lacc0 = MFMA_F16(ones, pB01, lacc0);                                      \
    Oc10 = MFMA_F16(vf01, pB11, Oc10);                                        \
    Oc11 = MFMA_F16(vf11, pB11, Oc11);                                        \
    lacc1 = MFMA_F16(ones, pB11, lacc1);                                      \
  }

  for (int tt = 0; tt < 32; tt += 2) {
    const int kvl = kvbase + tt * 64;
    PROCESS(kfA0, kfA1, kfA2, kfA3, kvl,
            LOADK(kfB0, kfB1, kfB2, kfB3, kvl + 64));
    if (tt + 2 < 32) {
      PROCESS(kfB0, kfB1, kfB2, kfB3, kvl + 64,
              LOADK(kfA0, kfA1, kfA2, kfA3, kvl + 128));
    } else {
      PROCESS(kfB0, kfB1, kfB2, kfB3, kvl + 64, );
    }
  }
#undef PROCESS
#undef LOADK

  // epilogue: partials into d_out (normalized O f16; m,l f32)
  const int b = bh >> 2, h = bh & 3;
  u16* OU = (u16*)outp;
  const size_t ob16 =
      (size_t)b * 2097152 + (size_t)((half * 4 + h) * 32) * 4096;

  {
    const float l0 = lacc0[0], inv0 = 1.0f / l0;
    const int q = q0 + r;
#pragma unroll
    for (int i = 0; i < 4; ++i) {
      OU[ob16 + (size_t)(g * 4 + i) * 4096 + q]      = f16bits(Oc00[i] * inv0);
      OU[ob16 + (size_t)(16 + g * 4 + i) * 4096 + q] = f16bits(Oc01[i] * inv0);
    }
    if (g == 0) {
      const size_t mlb =
          ((size_t)(b * 256 + 128 + (half * 4 + h) * 2)) * 4096 + q;
      outp[mlb] = mrun0;
      outp[mlb + 4096] = l0;
    }
  }
  {
    const float l1 = lacc1[0], inv1 = 1.0f / l1;
    const int q = q0 + 16 + r;
#pragma unroll
    for (int i = 0; i < 4; ++i) {
      OU[ob16 + (size_t)(g * 4 + i) * 4096 + q]      = f16bits(Oc10[i] * inv1);
      OU[ob16 + (size_t)(16 + g * 4 + i) * 4096 + q] = f16bits(Oc11[i] * inv1);
    }
    if (g == 0) {
      const size_t mlb =
          ((size_t)(b * 256 + 128 + (half * 4 + h) * 2)) * 4096 + q;
      outp[mlb] = mrun1;
      outp[mlb + 4096] = l1;
    }
  }
}

// ---------------------------------------------------------------------------
// Kernel C: merge KV-split partials + output projection (fp32 VALU).
// ---------------------------------------------------------------------------
__global__ __launch_bounds__(512) void outproj_kernel(
    const float* __restrict__ Wout, const float* __restrict__ bout,
    float* __restrict__ out)
{
  __shared__ float a_lds[64][129];
  const int j0  = blockIdx.x * 64;
  const int b   = blockIdx.y;
  const int tid = threadIdx.x;
  const int jl  = tid & 63;
  const int grp = tid >> 6;          // 0..7
  const int h   = grp & 3;
  const int dup = grp >> 2;          // d-half: 0 -> d 0..15, 1 -> d 16..31
  const int j   = j0 + jl;

  // merge weights for (b, j, h)
  const size_t mlb0 = ((size_t)(b * 256 + 128 + h * 2)) * 4096 + j;       // half 0
  const size_t mlb1 = ((size_t)(b * 256 + 128 + 8 + h * 2)) * 4096 + j;   // half 1
  const float m_a = out[mlb0], l_a = out[mlb0 + 4096];
  const float m_b = out[mlb1], l_b = out[mlb1 + 4096];
  const float M = fmaxf(m_a, m_b);
  float w_a = l_a * fexp2(m_a - M);
  float w_b = l_b * fexp2(m_b - M);
  const float winv = 1.0f / (w_a + w_b);
  w_a *= winv; w_b *= winv;

  const u16* OU = (const u16*)out;
  const size_t ob16 = (size_t)b * 2097152;
#pragma unroll
  for (int k = 0; k < 16; ++k) {
    const int dd = dup * 16 + k;
    const int ch = h * 32 + dd;
    const float oa = f16val(OU[ob16 + (size_t)ch * 4096 + j]);
    const float obv = f16val(OU[ob16 + (size_t)(128 + ch) * 4096 + j]);
    a_lds[jl][ch] = w_a * oa + w_b * obv;
  }
  __syncthreads();

  const int o0 = grp * 32;
#pragma unroll
  for (int og = 0; og < 4; ++og) {
    const int ob8 = o0 + og * 8;
    float acc[8];
#pragma unroll
    for (int oo = 0; oo < 8; ++oo) acc[oo] = bout[ob8 + oo];
    for (int ch = 0; ch < 128; ch += 4) {
#pragma unroll
      for (int c2 = 0; c2 < 4; ++c2) {
        const float a = a_lds[jl][ch + c2];
#pragma unroll
        for (int oo = 0; oo < 8; ++oo)
          acc[oo] = fmaf(Wout[(ob8 + oo) * 128 + ch + c2], a, acc[oo]);
      }
    }
#pragma unroll
    for (int oo = 0; oo < 8; ++oo)
      out[((size_t)(b * 256 + ob8 + oo)) * 4096 + j] = acc[oo];
  }
}

// ---------------------------------------------------------------------------
extern "C" void kernel_launch(void* const* d_in, const int* in_sizes, int n_in,
                              void* d_out, int out_size, void* d_ws, size_t ws_size,
                              hipStream_t stream) {
  const float* x    = (const float*)d_in[0];
  const float* Wq   = (const float*)d_in[1];
  const float* Wk   = (const float*)d_in[2];
  const float* Wv   = (const float*)d_in[3];
  const float* Wout = (const float*)d_in[4];
  const float* bout = (const float*)d_in[5];
  float* out = (float*)d_out;

  // workspace: 12 MiB (partials live inside d_out)
  char* ws = (char*)d_ws;
  u16* Qw = (u16*)(ws);                 // 4 MiB  [16][4096][32] f16
  u16* Kw = (u16*)(ws + (4u << 20));    // 4 MiB  [16][4096][32] f16
  u16* Vw = (u16*)(ws + (8u << 20));    // 4 MiB  [16][32][4096] f16 (perm)

  qkv_proj_kernel<<<dim3(64, 4), 512, 0, stream>>>(x, Wq, Wk, Wv, Qw, Kw, Vw);
  attn_kernel<<<dim3(1024), 256, 0, stream>>>(Qw, Kw, Vw, out);
  outproj_kernel<<<dim3(64, 4), 512, 0, stream>>>(Wout, bout, out);
}

// Round 7
// 176.807 us; speedup vs baseline: 1.3384x; 1.0272x over previous
//
#include <hip/hip_runtime.h>
#include <hip/hip_fp16.h>
#include <math.h>

typedef _Float16 f16x8 __attribute__((ext_vector_type(8)));
typedef float    f32x4 __attribute__((ext_vector_type(4)));
typedef unsigned int u32x4 __attribute__((ext_vector_type(4)));
typedef unsigned short u16;
typedef unsigned int   u32;

#define MFMA_F16(a, b, c) __builtin_amdgcn_mfma_f32_16x16x32_f16((a), (b), (c), 0, 0, 0)

#define NSP 4096
// (1/sqrt(32)) * log2(e): fold softmax scale and exp2 conversion into Q
#define QK_SCALE (0.17677669529663687f * 1.4426950408889634f)

__device__ __forceinline__ float fexp2(float x) {
#if __has_builtin(__builtin_amdgcn_exp2f)
  return __builtin_amdgcn_exp2f(x);
#else
  return exp2f(x);
#endif
}

__device__ __forceinline__ u32 pk_f16(float a, float b) {
#if __has_builtin(__builtin_amdgcn_cvt_pkrtz)
  return __builtin_bit_cast(u32, __builtin_amdgcn_cvt_pkrtz(a, b));
#else
  u16 lo = __builtin_bit_cast(u16, (_Float16)a);
  u16 hi = __builtin_bit_cast(u16, (_Float16)b);
  return (u32)lo | ((u32)hi << 16);
#endif
}

__device__ __forceinline__ u16 f16bits(float a) {
  return __builtin_bit_cast(u16, (_Float16)a);
}

__device__ __forceinline__ float f16val(u16 v) {
  return (float)__builtin_bit_cast(_Float16, v);
}

// ---------------------------------------------------------------------------
// Kernel A: QKV projection (unchanged).
// Q,K stored [bh][n][32] f16 (Q pre-scaled by QK_SCALE); V stored transposed
// [bh][32][n] with per-32-column MFMA k-slot permutation.
// ---------------------------------------------------------------------------
__global__ __launch_bounds__(512) void qkv_proj_kernel(
    const float* __restrict__ x, const float* __restrict__ Wq,
    const float* __restrict__ Wk, const float* __restrict__ Wv,
    u16* __restrict__ Qo, u16* __restrict__ Ko, u16* __restrict__ Vo)
{
  const int b  = blockIdx.y;
  const int j0 = blockIdx.x * 64;
  const int tid  = threadIdx.x;
  const int wave = tid >> 6, lane = tid & 63;
  const int g = lane >> 4, r = lane & 15;
  const float* xb = x + (size_t)b * 256 * NSP;

  const f32x4 ZERO4 = {0.f, 0.f, 0.f, 0.f};
  f32x4 acc[3][4];
#pragma unroll
  for (int m = 0; m < 3; ++m)
#pragma unroll
    for (int n = 0; n < 4; ++n) acc[m][n] = ZERO4;

  for (int kc = 0; kc < 8; ++kc) {
    f16x8 bfrag[4];
#pragma unroll
    for (int nt = 0; nt < 4; ++nt) {
      const float* src = xb + (size_t)(kc * 32 + g * 8) * NSP + j0 + nt * 16 + r;
      f16x8 f;
#pragma unroll
      for (int i = 0; i < 8; ++i) f[i] = (_Float16)src[(size_t)i * NSP];
      bfrag[nt] = f;
    }
#pragma unroll
    for (int mm = 0; mm < 3; ++mm) {
      const int o_tile = wave * 48 + mm * 16;
      const float* wsrc = (o_tile < 128) ? Wq : ((o_tile < 256) ? Wk : Wv);
      const float* arow = wsrc + ((o_tile & 127) + r) * 256 + kc * 32 + g * 8;
      f16x8 af;
#pragma unroll
      for (int i = 0; i < 8; ++i) af[i] = (_Float16)arow[i];
#pragma unroll
      for (int nt = 0; nt < 4; ++nt)
        acc[mm][nt] = MFMA_F16(af, bfrag[nt], acc[mm][nt]);
    }
  }

#pragma unroll
  for (int mm = 0; mm < 3; ++mm) {
    const int o_tile = wave * 48 + mm * 16;
    const int part = o_tile >> 7;            // 0=Q 1=K 2=V
    const int o_in = o_tile & 127;
    const int head = o_in >> 5;
    const int dbase = (o_in & 31) + g * 4;
#pragma unroll
    for (int nt = 0; nt < 4; ++nt) {
      const int j = j0 + nt * 16 + r;
      if (part < 2) {
        u16* dst = (part == 0) ? Qo : Ko;
        const float sc = (part == 0) ? QK_SCALE : 1.0f;
        const size_t base = ((size_t)((b * 4 + head) * NSP + j)) * 32 + dbase;
        const u32 p01 = pk_f16(acc[mm][nt][0] * sc, acc[mm][nt][1] * sc);
        const u32 p23 = pk_f16(acc[mm][nt][2] * sc, acc[mm][nt][3] * sc);
        *(u32*)(dst + base)     = p01;
        *(u32*)(dst + base + 2) = p23;
      } else {
        // permuted V store: within each 32-col block, kv j -> slot s
        const int jb = j & ~31, off = j & 31;
        const int s = (((off >> 2) & 3) << 3) | (((off >> 4) & 1) << 2) | (off & 3);
#pragma unroll
        for (int i = 0; i < 4; ++i)
          Vo[((size_t)((b * 4 + head) * 32 + dbase + i)) * NSP + jb + s] =
              f16bits(acc[mm][nt][i]);
      }
    }
  }
}

// ---------------------------------------------------------------------------
// Kernel B: flash attention, 32 q-rows/wave, KV-split x2, register-resident P.
// ROUND 7 CHANGES (VALU-count reduction; latency-bound per round-6 counters):
//  - mC = splat(-mrun) folded into QK^T C-operand: S' = K*q - mrun comes out
//    of the matrix pipe pre-subtracted (kills 32 v_sub/iter; defer test is
//    tm' > 8 vs constant). mrun init 0 (NOT -inf: avoids inf-inf NaN; P<=2^8
//    bounded, f16-safe).
//  - Running pointers + immediate offsets for K (1 ptr, 0/1024/2048/3072B)
//    and V (2 ptrs, 0/64B), replacing per-load 64-bit address math.
//  - max3-shaped reduction tree (v_max3_f32 fusion).
// ---------------------------------------------------------------------------
__global__ __launch_bounds__(256, 3) void attn_kernel(
    const u16* __restrict__ Qg, const u16* __restrict__ Kg,
    const u16* __restrict__ Vg, float* __restrict__ outp)
{
  const int d    = blockIdx.x;
  const int bh   = (d & 7) * 2 + ((d >> 3) & 1);   // XCD-local bh pair
  const int half = (d >> 4) & 1;
  const int qt   = d >> 5;                          // 0..31
  const int wave = threadIdx.x >> 6, lane = threadIdx.x & 63;
  const int g = lane >> 4, r = lane & 15;
  const int q0 = qt * 128 + wave * 32;              // this wave: 32 q-rows
  const int kvbase = half * 2048;                   // this block: 2048 kv

  const size_t qkb = (size_t)bh * NSP * 32;
  const u16* Kp = Kg + qkb;                         // [n][32]
  const u16* Vp = Vg + (size_t)bh * 32 * NSP;       // [32][n] permuted

  const f16x8 qf0 = *(const f16x8*)(Qg + qkb + (size_t)(q0 + r) * 32 + g * 8);
  const f16x8 qf1 = *(const f16x8*)(Qg + qkb + (size_t)(q0 + 16 + r) * 32 + g * 8);

  const f32x4 ZERO4 = {0.f, 0.f, 0.f, 0.f};
  f32x4 Oc00 = ZERO4, Oc01 = ZERO4, Oc10 = ZERO4, Oc11 = ZERO4;
  f32x4 lacc0 = ZERO4, lacc1 = ZERO4;
  f32x4 mC0 = ZERO4, mC1 = ZERO4;     // splat(-mrun)
  float mrun0 = 0.0f, mrun1 = 0.0f;

  f16x8 ones;
#pragma unroll
  for (int i = 0; i < 8; ++i) ones[i] = (_Float16)1.0f;

  // running pointers (strength-reduced addressing)
  const u16* kptr  = Kp + (size_t)(kvbase + r) * 32 + g * 8;   // next K tile
  const u16* vptr0 = Vp + (size_t)r * NSP + kvbase + g * 8;    // rows 0..15
  const u16* vptr1 = vptr0 + (size_t)16 * NSP;                 // rows 16..31

  f16x8 kfA0, kfA1, kfA2, kfA3, kfB0, kfB1, kfB2, kfB3;
#define LOADK(d0, d1, d2, d3)                                                 \
  {                                                                           \
    d0 = *(const f16x8*)(kptr);                                               \
    d1 = *(const f16x8*)(kptr + 512);    /* +16 rows, 1024B imm */            \
    d2 = *(const f16x8*)(kptr + 1024);   /* 2048B imm */                      \
    d3 = *(const f16x8*)(kptr + 1536);   /* 3072B imm */                      \
    kptr += 2048;                        /* advance one 64-row tile */        \
  }

  LOADK(kfA0, kfA1, kfA2, kfA3);

#define PROCESS(K0, K1, K2, K3, PREFETCH)                                     \
  {                                                                           \
    /* V loads first (used ~300cy later, after softmax) */                    \
    const f16x8 vf00 = *(const f16x8*)(vptr0);                                \
    const f16x8 vf01 = *(const f16x8*)(vptr0 + 32);   /* +64B imm */          \
    const f16x8 vf10 = *(const f16x8*)(vptr1);                                \
    const f16x8 vf11 = *(const f16x8*)(vptr1 + 32);                           \
    vptr0 += 64; vptr1 += 64;                                                 \
    PREFETCH;                                                                 \
    /* QK^T with -mrun folded into C: S' = K*q - mrun */                      \
    f32x4 S00 = MFMA_F16(K0, qf0, mC0);                                       \
    f32x4 S01 = MFMA_F16(K1, qf0, mC0);                                       \
    f32x4 S02 = MFMA_F16(K2, qf0, mC0);                                       \
    f32x4 S03 = MFMA_F16(K3, qf0, mC0);                                       \
    f32x4 S10 = MFMA_F16(K0, qf1, mC1);                                       \
    f32x4 S11 = MFMA_F16(K1, qf1, mC1);                                       \
    f32x4 S12 = MFMA_F16(K2, qf1, mC1);                                       \
    f32x4 S13 = MFMA_F16(K3, qf1, mC1);                                       \
    /* row max (shifted space), max3-shaped tree */                           \
    float a0 = fmaxf(fmaxf(S00[0], S00[1]), S00[2]);                          \
    float a1 = fmaxf(fmaxf(S00[3], S01[0]), S01[1]);                          \
    float a2 = fmaxf(fmaxf(S01[2], S01[3]), S02[0]);                          \
    float a3 = fmaxf(fmaxf(S02[1], S02[2]), S02[3]);                          \
    float a4 = fmaxf(fmaxf(S03[0], S03[1]), S03[2]);                          \
    float tm0 = fmaxf(fmaxf(fmaxf(a0, a1), a2), fmaxf(fmaxf(a3, a4), S03[3]));\
    float b0 = fmaxf(fmaxf(S10[0], S10[1]), S10[2]);                          \
    float b1 = fmaxf(fmaxf(S10[3], S11[0]), S11[1]);                          \
    float b2 = fmaxf(fmaxf(S11[2], S11[3]), S12[0]);                          \
    float b3 = fmaxf(fmaxf(S12[1], S12[2]), S12[3]);                          \
    float b4 = fmaxf(fmaxf(S13[0], S13[1]), S13[2]);                          \
    float tm1 = fmaxf(fmaxf(fmaxf(b0, b1), b2), fmaxf(fmaxf(b3, b4), S13[3]));\
    tm0 = fmaxf(tm0, __shfl_xor(tm0, 16));                                    \
    tm0 = fmaxf(tm0, __shfl_xor(tm0, 32));                                    \
    tm1 = fmaxf(tm1, __shfl_xor(tm1, 16));                                    \
    tm1 = fmaxf(tm1, __shfl_xor(tm1, 32));                                    \
    /* T13 defer-max vs constant threshold (rare branch) */                   \
    if (__any((tm0 > 8.0f) || (tm1 > 8.0f))) {                                \
      const float d0 = fmaxf(tm0, 0.0f);                                      \
      const float d1 = fmaxf(tm1, 0.0f);                                      \
      const float al0 = fexp2(-d0);                                           \
      const float al1 = fexp2(-d1);                                           \
      mrun0 += d0; mrun1 += d1;                                               \
      mC0[0] -= d0; mC0[1] -= d0; mC0[2] -= d0; mC0[3] -= d0;                 \
      mC1[0] -= d1; mC1[1] -= d1; mC1[2] -= d1; mC1[3] -= d1;                 \
      S00[0] -= d0; S00[1] -= d0; S00[2] -= d0; S00[3] -= d0;                 \
      S01[0] -= d0; S01[1] -= d0; S01[2] -= d0; S01[3] -= d0;                 \
      S02[0] -= d0; S02[1] -= d0; S02[2] -= d0; S02[3] -= d0;                 \
      S03[0] -= d0; S03[1] -= d0; S03[2] -= d0; S03[3] -= d0;                 \
      S10[0] -= d1; S10[1] -= d1; S10[2] -= d1; S10[3] -= d1;                 \
      S11[0] -= d1; S11[1] -= d1; S11[2] -= d1; S11[3] -= d1;                 \
      S12[0] -= d1; S12[1] -= d1; S12[2] -= d1; S12[3] -= d1;                 \
      S13[0] -= d1; S13[1] -= d1; S13[2] -= d1; S13[3] -= d1;                 \
      Oc00[0] *= al0; Oc00[1] *= al0; Oc00[2] *= al0; Oc00[3] *= al0;         \
      Oc01[0] *= al0; Oc01[1] *= al0; Oc01[2] *= al0; Oc01[3] *= al0;         \
      lacc0[0] *= al0; lacc0[1] *= al0; lacc0[2] *= al0; lacc0[3] *= al0;     \
      Oc10[0] *= al1; Oc10[1] *= al1; Oc10[2] *= al1; Oc10[3] *= al1;         \
      Oc11[0] *= al1; Oc11[1] *= al1; Oc11[2] *= al1; Oc11[3] *= al1;         \
      lacc1[0] *= al1; lacc1[1] *= al1; lacc1[2] *= al1; lacc1[3] *= al1;     \
    }                                                                         \
    /* P = exp2(S'), pack in-lane */                                          \
    u32x4 w0, w1, w2, w3;                                                     \
    w0[0] = pk_f16(fexp2(S00[0]), fexp2(S00[1]));                             \
    w0[1] = pk_f16(fexp2(S00[2]), fexp2(S00[3]));                             \
    w0[2] = pk_f16(fexp2(S01[0]), fexp2(S01[1]));                             \
    w0[3] = pk_f16(fexp2(S01[2]), fexp2(S01[3]));                             \
    w1[0] = pk_f16(fexp2(S02[0]), fexp2(S02[1]));                             \
    w1[1] = pk_f16(fexp2(S02[2]), fexp2(S02[3]));                             \
    w1[2] = pk_f16(fexp2(S03[0]), fexp2(S03[1]));                             \
    w1[3] = pk_f16(fexp2(S03[2]), fexp2(S03[3]));                             \
    w2[0] = pk_f16(fexp2(S10[0]), fexp2(S10[1]));                             \
    w2[1] = pk_f16(fexp2(S10[2]), fexp2(S10[3]));                             \
    w2[2] = pk_f16(fexp2(S11[0]), fexp2(S11[1]));                             \
    w2[3] = pk_f16(fexp2(S11[2]), fexp2(S11[3]));                             \
    w3[0] = pk_f16(fexp2(S12[0]), fexp2(S12[1]));                             \
    w3[1] = pk_f16(fexp2(S12[2]), fexp2(S12[3]));                             \
    w3[2] = pk_f16(fexp2(S13[0]), fexp2(S13[1]));                             \
    w3[3] = pk_f16(fexp2(S13[2]), fexp2(S13[3]));                             \
    const f16x8 pB00 = __builtin_bit_cast(f16x8, w0);                         \
    const f16x8 pB01 = __builtin_bit_cast(f16x8, w1);                         \
    const f16x8 pB10 = __builtin_bit_cast(f16x8, w2);                         \
    const f16x8 pB11 = __builtin_bit_cast(f16x8, w3);                         \
    /* PV + row-sums: 12 MFMAs */                                             \
    Oc00 = MFMA_F16(vf00, pB00, Oc00);                                        \
    Oc01 = MFMA_F16(vf10, pB00, Oc01);                                        \
    lacc0 = MFMA_F16(ones, pB00, lacc0);                                      \
    Oc10 = MFMA_F16(vf00, pB10, Oc10);                                        \
    Oc11 = MFMA_F16(vf10, pB10, Oc11);                                        \
    lacc1 = MFMA_F16(ones, pB10, lacc1);                                      \
    Oc00 = MFMA_F16(vf01, pB01, Oc00);                                        \
    Oc01 = MFMA_F16(vf11, pB01, Oc01);                                        \
    lacc0 = MFMA_F16(ones, pB01, lacc0);                                      \
    Oc10 = MFMA_F16(vf01, pB11, Oc10);                                        \
    Oc11 = MFMA_F16(vf11, pB11, Oc11);                                        \
    lacc1 = MFMA_F16(ones, pB11, lacc1);                                      \
  }

  for (int tt = 0; tt < 32; tt += 2) {
    PROCESS(kfA0, kfA1, kfA2, kfA3, LOADK(kfB0, kfB1, kfB2, kfB3));
    if (tt + 2 < 32) {
      PROCESS(kfB0, kfB1, kfB2, kfB3, LOADK(kfA0, kfA1, kfA2, kfA3));
    } else {
      PROCESS(kfB0, kfB1, kfB2, kfB3, );
    }
  }
#undef PROCESS
#undef LOADK

  // epilogue: partials into d_out (normalized O f16; m,l f32)
  const int b = bh >> 2, h = bh & 3;
  u16* OU = (u16*)outp;
  const size_t ob16 =
      (size_t)b * 2097152 + (size_t)((half * 4 + h) * 32) * 4096;

  {
    const float l0 = lacc0[0], inv0 = 1.0f / l0;
    const int q = q0 + r;
#pragma unroll
    for (int i = 0; i < 4; ++i) {
      OU[ob16 + (size_t)(g * 4 + i) * 4096 + q]      = f16bits(Oc00[i] * inv0);
      OU[ob16 + (size_t)(16 + g * 4 + i) * 4096 + q] = f16bits(Oc01[i] * inv0);
    }
    if (g == 0) {
      const size_t mlb =
          ((size_t)(b * 256 + 128 + (half * 4 + h) * 2)) * 4096 + q;
      outp[mlb] = mrun0;
      outp[mlb + 4096] = l0;
    }
  }
  {
    const float l1 = lacc1[0], inv1 = 1.0f / l1;
    const int q = q0 + 16 + r;
#pragma unroll
    for (int i = 0; i < 4; ++i) {
      OU[ob16 + (size_t)(g * 4 + i) * 4096 + q]      = f16bits(Oc10[i] * inv1);
      OU[ob16 + (size_t)(16 + g * 4 + i) * 4096 + q] = f16bits(Oc11[i] * inv1);
    }
    if (g == 0) {
      const size_t mlb =
          ((size_t)(b * 256 + 128 + (half * 4 + h) * 2)) * 4096 + q;
      outp[mlb] = mrun1;
      outp[mlb + 4096] = l1;
    }
  }
}

// ---------------------------------------------------------------------------
// Kernel C: merge KV-split partials + output projection (fp32 VALU).
// ---------------------------------------------------------------------------
__global__ __launch_bounds__(512) void outproj_kernel(
    const float* __restrict__ Wout, const float* __restrict__ bout,
    float* __restrict__ out)
{
  __shared__ float a_lds[64][129];
  const int j0  = blockIdx.x * 64;
  const int b   = blockIdx.y;
  const int tid = threadIdx.x;
  const int jl  = tid & 63;
  const int grp = tid >> 6;          // 0..7
  const int h   = grp & 3;
  const int dup = grp >> 2;          // d-half: 0 -> d 0..15, 1 -> d 16..31
  const int j   = j0 + jl;

  // merge weights for (b, j, h)
  const size_t mlb0 = ((size_t)(b * 256 + 128 + h * 2)) * 4096 + j;       // half 0
  const size_t mlb1 = ((size_t)(b * 256 + 128 + 8 + h * 2)) * 4096 + j;   // half 1
  const float m_a = out[mlb0], l_a = out[mlb0 + 4096];
  const float m_b = out[mlb1], l_b = out[mlb1 + 4096];
  const float M = fmaxf(m_a, m_b);
  float w_a = l_a * fexp2(m_a - M);
  float w_b = l_b * fexp2(m_b - M);
  const float winv = 1.0f / (w_a + w_b);
  w_a *= winv; w_b *= winv;

  const u16* OU = (const u16*)out;
  const size_t ob16 = (size_t)b * 2097152;
#pragma unroll
  for (int k = 0; k < 16; ++k) {
    const int dd = dup * 16 + k;
    const int ch = h * 32 + dd;
    const float oa = f16val(OU[ob16 + (size_t)ch * 4096 + j]);
    const float obv = f16val(OU[ob16 + (size_t)(128 + ch) * 4096 + j]);
    a_lds[jl][ch] = w_a * oa + w_b * obv;
  }
  __syncthreads();

  const int o0 = grp * 32;
#pragma unroll
  for (int og = 0; og < 4; ++og) {
    const int ob8 = o0 + og * 8;
    float acc[8];
#pragma unroll
    for (int oo = 0; oo < 8; ++oo) acc[oo] = bout[ob8 + oo];
    for (int ch = 0; ch < 128; ch += 4) {
#pragma unroll
      for (int c2 = 0; c2 < 4; ++c2) {
        const float a = a_lds[jl][ch + c2];
#pragma unroll
        for (int oo = 0; oo < 8; ++oo)
          acc[oo] = fmaf(Wout[(ob8 + oo) * 128 + ch + c2], a, acc[oo]);
      }
    }
#pragma unroll
    for (int oo = 0; oo < 8; ++oo)
      out[((size_t)(b * 256 + ob8 + oo)) * 4096 + j] = acc[oo];
  }
}

// ---------------------------------------------------------------------------
extern "C" void kernel_launch(void* const* d_in, const int* in_sizes, int n_in,
                              void* d_out, int out_size, void* d_ws, size_t ws_size,
                              hipStream_t stream) {
  const float* x    = (const float*)d_in[0];
  const float* Wq   = (const float*)d_in[1];
  const float* Wk   = (const float*)d_in[2];
  const float* Wv   = (const float*)d_in[3];
  const float* Wout = (const float*)d_in[4];
  const float* bout = (const float*)d_in[5];
  float* out = (float*)d_out;

  // workspace: 12 MiB (partials live inside d_out)
  char* ws = (char*)d_ws;
  u16* Qw = (u16*)(ws);                 // 4 MiB  [16][4096][32] f16
  u16* Kw = (u16*)(ws + (4u << 20));    // 4 MiB  [16][4096][32] f16
  u16* Vw = (u16*)(ws + (8u << 20));    // 4 MiB  [16][32][4096] f16 (perm)

  qkv_proj_kernel<<<dim3(64, 4), 512, 0, stream>>>(x, Wq, Wk, Wv, Qw, Kw, Vw);
  attn_kernel<<<dim3(1024), 256, 0, stream>>>(Qw, Kw, Vw, out);
  outproj_kernel<<<dim3(64, 4), 512, 0, stream>>>(Wout, bout, out);
}